// Round 1
// baseline (958.466 us; speedup 1.0000x reference)
//
#include <hip/hip_runtime.h>

#define B_  2
#define S_  2048
#define D_  4096
#define H_  16
#define HD_ 256
#define N1  12288
#define N2  4096

typedef __attribute__((ext_vector_type(8))) short  bf8_t;   // 8 bf16 (4 VGPRs)
typedef __attribute__((ext_vector_type(8))) ushort us8_t;
typedef __attribute__((ext_vector_type(4))) float  f4_t;

__device__ __forceinline__ ushort f2bf(float f) {
  union { float f; uint u; } c; c.f = f;
  uint u = c.u;
  return (ushort)((u + 0x7fffu + ((u >> 16) & 1u)) >> 16);  // RNE
}
__device__ __forceinline__ float bf2f(ushort b) {
  union { uint u; float f; } c; c.u = ((uint)b) << 16;
  return c.f;
}

#define MFMA16(a, b, c) __builtin_amdgcn_mfma_f32_16x16x32_bf16((a), (b), (c), 0, 0, 0)

__device__ __forceinline__ void gload16(const void* g, void* l) {
  __builtin_amdgcn_global_load_lds(
      (const __attribute__((address_space(1))) void*)g,
      (__attribute__((address_space(3))) void*)l, 16, 0, 0);
}

// ---------------------------------------------------------------------------
// hidden f32 -> bf16
// ---------------------------------------------------------------------------
__global__ __launch_bounds__(256) void cvt_bf16(const float* __restrict__ x,
                                                ushort* __restrict__ y)
{
  const size_t i = ((size_t)blockIdx.x * 256 + threadIdx.x) * 8;
  const float4 a = *(const float4*)(x + i);
  const float4 b = *(const float4*)(x + i + 4);
  us8_t o;
  o[0] = f2bf(a.x); o[1] = f2bf(a.y); o[2] = f2bf(a.z); o[3] = f2bf(a.w);
  o[4] = f2bf(b.x); o[5] = f2bf(b.y); o[6] = f2bf(b.z); o[7] = f2bf(b.w);
  *(us8_t*)(y + i) = o;
}

// ---------------------------------------------------------------------------
// GPTQ dequant -> W^T bf16 [N][4096]  (one-shot, memory-bound)
// ---------------------------------------------------------------------------
__global__ __launch_bounds__(256) void dequant_w(
    const int* __restrict__ qw, const int* __restrict__ qz,
    const float* __restrict__ sc, ushort* __restrict__ wt, const int N)
{
  __shared__ ushort T[64][72];
  const int tid = threadIdx.x;
  const int n0 = blockIdx.x * 64, k0 = blockIdx.y * 64;
  const int g = k0 >> 7;                           // GS=128
  const int nn  = tid & 63;
  const int kw0 = tid >> 6;                        // 0..3
  const int gn = n0 + nn;
  const int zw = qz[g * (N >> 3) + (gn >> 3)];
  const float zp = (float)(((zw >> ((gn & 7) * 4)) & 15) + 1);
  const float scale = sc[g * N + gn];
  const float szp = scale * zp;
#pragma unroll
  for (int t = 0; t < 2; ++t) {
    const int kw = kw0 + t * 4;
    const uint w = (uint)qw[(size_t)((k0 >> 3) + kw) * N + gn];
    us8_t pk;
#pragma unroll
    for (int j = 0; j < 8; ++j)
      pk[j] = f2bf(fmaf((float)((w >> (4 * j)) & 15u), scale, -szp));
    *(us8_t*)(&T[nn][kw * 8]) = pk;
  }
  __syncthreads();
#pragma unroll
  for (int t = 0; t < 2; ++t) {
    const int u = tid + t * 256;
    const int r = u >> 3, c = u & 7;
    *(uint4*)(wt + (size_t)(n0 + r) * 4096 + k0 + c * 8) = *(uint4*)(&T[r][c * 8]);
  }
}

// ---------------------------------------------------------------------------
// 256x256 deep-pipelined bf16 GEMM core (T3+T4+T5).
//
// BK=32, 4-deep circular LDS double..quad buffer (128 KiB), 8 waves.
// Pipeline invariants:
//   - iteration t: STAGE tile t+3 into buf[(t+3)&3] (== buf[(t-1)&3], whose
//     last ds_read completed before the previous iteration's barrier),
//     ds_read + MFMA tile t from buf[t&3],
//     then s_waitcnt vmcnt(8)  (3 tiles x 4 loads in flight; the wait
//     retires exactly tile t+1's 4 loads)  BEFORE s_barrier, so after the
//     barrier every thread's tile-t+1 loads have landed.
//   - vmcnt never drains to 0 in the main loop (T4); tail peels 8->4->0.
//   - LDS swizzle at row-pair granularity: slot s of 128B pair p holds
//     global 16B chunk s^(p&7); applied on BOTH the (pre-swizzled) global
//     source of global_load_lds and the ds_read addresses.  64-lane b128
//     reads spread exactly 8 lanes per 16B bank-slot (balanced = 0 extra).
// ---------------------------------------------------------------------------
#define NT_ 128   /* 4096 / 32 */

#define STAGE_T(t_) do {                                                      \
    const int b_  = (t_) & 3;                                                 \
    const int kk_ = (t_) << 5;                                                \
    gload16(Arow0 + kk_,                     &As[b_][wave * 512]);            \
    gload16(Brow0 + kk_,                     &Bs[b_][wave * 512]);            \
    gload16(Arow0 + (size_t)128 * 4096 + kk_, &As[b_][4096 + wave * 512]);    \
    gload16(Brow0 + (size_t)128 * 4096 + kk_, &Bs[b_][4096 + wave * 512]);    \
  } while (0)

#define COMPUTE_T(t_) do {                                                    \
    const char* ab_ = (const char*)(&As[(t_) & 3][0]);                        \
    const char* bb_ = (const char*)(&Bs[(t_) & 3][0]);                        \
    bf8_t af[8], bfv[4];                                                      \
    _Pragma("unroll") for (int i = 0; i < 8; ++i)                             \
        af[i] = *(const bf8_t*)(ab_ + aoff[i]);                               \
    _Pragma("unroll") for (int j = 0; j < 4; ++j)                             \
        bfv[j] = *(const bf8_t*)(bb_ + boff[j]);                              \
    asm volatile("s_waitcnt lgkmcnt(0)" ::: "memory");                        \
    __builtin_amdgcn_sched_barrier(0);                                        \
    __builtin_amdgcn_s_setprio(1);                                            \
    _Pragma("unroll") for (int i = 0; i < 8; ++i)                             \
    _Pragma("unroll") for (int j = 0; j < 4; ++j)                             \
        acc[i][j] = MFMA16(af[i], bfv[j], acc[i][j]);                         \
    __builtin_amdgcn_s_setprio(0);                                            \
    __builtin_amdgcn_sched_barrier(0);                                        \
  } while (0)

#define WAITBAR(n_) do {                                                      \
    asm volatile("s_waitcnt vmcnt(" #n_ ")" ::: "memory");                    \
    __builtin_amdgcn_s_barrier();                                             \
    __builtin_amdgcn_sched_barrier(0);                                        \
  } while (0)

#define GEMM256_CORE(Ag_, Bg_)                                                \
  __shared__ ushort As[4][8192];                                              \
  __shared__ ushort Bs[4][8192];                                              \
  const int tid  = threadIdx.x;                                               \
  const int lane = tid & 63, wave = tid >> 6;                                 \
  const int quad = lane >> 4, l15 = lane & 15;                                \
  const int wm = wave >> 2, wn = wave & 3;                                    \
  const int gx = gridDim.x;                                                   \
  int lin = blockIdx.y * gx + blockIdx.x;                                     \
  lin = (lin & 7) * (gx << 1) + (lin >> 3); /* bijective: nwg = gx*16, %8==0 */\
  const int n0 = (lin >> 4) << 8;                                             \
  const int m0 = (lin & 15) << 8;                                             \
  f4_t acc[8][4];                                                             \
  _Pragma("unroll") for (int i = 0; i < 8; ++i)                               \
  _Pragma("unroll") for (int j = 0; j < 4; ++j)                               \
      acc[i][j] = (f4_t){0.f, 0.f, 0.f, 0.f};                                 \
  /* staging: linear chunk q = rr*512 + tid; p=q>>3 (128B pair), s=q&7 */     \
  const int pq   = tid >> 3;                                                  \
  const int gch  = (tid & 7) ^ (pq & 7);                                      \
  const int grow = 2 * pq + (gch >> 2);                                       \
  const int gcol = (gch & 3) * 8;                                             \
  const ushort* Arow0 = Ag_ + (size_t)(m0 + grow) * 4096 + gcol;              \
  const ushort* Brow0 = Bg_ + (size_t)(n0 + grow) * 4096 + gcol;              \
  /* ds_read offsets: row R -> pair p=R>>1, slot ((R&1)*4+quad)^(p&7) */      \
  const int h_ = l15 >> 1;                                                    \
  const int sx = ((l15 & 1) * 4 + quad) ^ h_;                                 \
  int aoff[8], boff[4];                                                       \
  _Pragma("unroll") for (int i = 0; i < 8; ++i)                               \
      aoff[i] = (((wm * 64 + i * 8 + h_) * 8) + sx) * 16;                     \
  _Pragma("unroll") for (int j = 0; j < 4; ++j)                               \
      boff[j] = (((wn * 32 + j * 8 + h_) * 8) + sx) * 16;                     \
  STAGE_T(0); STAGE_T(1); STAGE_T(2);                                         \
  WAITBAR(8);                                                                 \
  for (int t = 0; t < NT_ - 3; ++t) {                                         \
    STAGE_T(t + 3);                                                           \
    COMPUTE_T(t);                                                             \
    WAITBAR(8);                                                               \
  }                                                                           \
  COMPUTE_T(NT_ - 3);                                                         \
  WAITBAR(4);                                                                 \
  COMPUTE_T(NT_ - 2);                                                         \
  WAITBAR(0);                                                                 \
  COMPUTE_T(NT_ - 1);

__global__ __launch_bounds__(512, 2) void gemm_fast_qkv(
    const ushort* __restrict__ A, const ushort* __restrict__ BT,
    ushort* __restrict__ wq, ushort* __restrict__ wk, ushort* __restrict__ wv)
{
  GEMM256_CORE(A, BT)
  // epilogue: scatter to (which, B, H, S, hd) bf16; q prescaled by 1/sqrt(hd)
  // n0 is a multiple of 256 -> tile covers exactly one head's 256 dims.
  const int which = n0 >> 12;
  const int nh = (n0 & 4095) >> 8;
  const int bb = m0 >> 11;
  const int s_base = m0 & 2047;
  ushort* dst = (which == 0) ? wq : (which == 1) ? wk : wv;
  const float osc = (which == 0) ? 0.0625f : 1.0f;
  const size_t rowbase = ((size_t)bb * H_ + nh) * S_;
#pragma unroll
  for (int i = 0; i < 8; ++i) {
#pragma unroll
    for (int r = 0; r < 4; ++r) {
      const int s = s_base + wm * 128 + i * 16 + quad * 4 + r;
      ushort* prow = dst + (rowbase + s) * HD_ + wn * 64 + l15;
#pragma unroll
      for (int j = 0; j < 4; ++j)
        prow[j * 16] = f2bf(acc[i][j][r] * osc);
    }
  }
}

__global__ __launch_bounds__(512, 2) void gemm_fast_out(
    const ushort* __restrict__ A, const ushort* __restrict__ BT,
    float* __restrict__ out)
{
  GEMM256_CORE(A, BT)
#pragma unroll
  for (int i = 0; i < 8; ++i) {
#pragma unroll
    for (int r = 0; r < 4; ++r) {
      float* prow = out + (size_t)(m0 + wm * 128 + i * 16 + quad * 4 + r) * D_
                        + n0 + wn * 64 + l15;
#pragma unroll
      for (int j = 0; j < 4; ++j)
        prow[j * 16] = acc[i][j][r];
    }
  }
}

// ---------------------------------------------------------------------------
// RoPE in-place on q and k (q is prescaled; rotation commutes with scalar)
// ---------------------------------------------------------------------------
__global__ __launch_bounds__(256) void rope_qk(ushort* __restrict__ q, ushort* __restrict__ k)
{
  const int idx = blockIdx.x * 256 + threadIdx.x;
  const int i   = idx & 31;
  const int row = (idx >> 5) & 0xFFFF;
  const int buf = idx >> 21;
  const int s   = row & 2047;
  ushort* p = (buf ? k : q) + (size_t)row * HD_ + 2 * i;
  const float inv_freq = expf((float)(2 * i) * -0.14391157f);
  const float ang = (float)s * inv_freq;
  float sn, cs;
  sincosf(ang, &sn, &cs);
  uint pr = *(uint*)p;
  const float x1 = bf2f((ushort)(pr & 0xFFFF));
  const float x2 = bf2f((ushort)(pr >> 16));
  const uint lo = f2bf(x1 * cs - x2 * sn);
  const uint hi = f2bf(x2 * cs + x1 * sn);
  *(uint*)p = lo | (hi << 16);
}

// ---------------------------------------------------------------------------
// V (B,H,S,hd) -> VT (B,H,hd,S)
// ---------------------------------------------------------------------------
__global__ __launch_bounds__(256) void transpose_v(const ushort* __restrict__ v,
                                                   ushort* __restrict__ vt)
{
  __shared__ uint t32[64][65];
  const int tid = threadIdx.x;
  const int s0 = blockIdx.x * 64, d0 = blockIdx.y * 64, bh = blockIdx.z;
  const ushort* src = v + ((size_t)bh * S_ + s0) * HD_ + d0;
#pragma unroll
  for (int i = 0; i < 2; ++i) {
    const int u = tid + 256 * i;
    const int r = u >> 3, cu = u & 7;
    const uint4 val = *(const uint4*)(src + (size_t)r * HD_ + cu * 8);
    const ushort* pv = (const ushort*)&val;
#pragma unroll
    for (int j = 0; j < 8; ++j) t32[r][cu * 8 + j] = pv[j];
  }
  __syncthreads();
  ushort* dstb = vt + ((size_t)bh * HD_ + d0) * S_ + s0;
#pragma unroll
  for (int i = 0; i < 2; ++i) {
    const int u = tid + 256 * i;
    const int dr = u >> 3, cu = u & 7;
    union { ushort u16[8]; uint4 v4; } tmp;
#pragma unroll
    for (int j = 0; j < 8; ++j) tmp.u16[j] = (ushort)t32[cu * 8 + j][dr];
    *(uint4*)(dstb + (size_t)dr * S_ + cu * 8) = tmp.v4;
  }
}

// ---------------------------------------------------------------------------
// Flash attention v2: ones-column l, rescale-skip, swizzled global_load_lds K
// Q is prescaled by 1/sqrt(hd). Grid: (bh, qtile) with qtile heavy-first.
// ---------------------------------------------------------------------------
__global__ __launch_bounds__(256) void flash_attn2(
    const ushort* __restrict__ Q, const ushort* __restrict__ K,
    const ushort* __restrict__ VT, ushort* __restrict__ attn)
{
  __shared__ ushort Kls[8192];         // 32 keys x 256 c, 16B-chunk swizzled
  __shared__ ushort Vls[256][40];      // [d][key] +8 pad
  __shared__ ushort Pls[4][16][40];    // per-wave P roundtrip
  const int tid  = threadIdx.x;
  const int lane = tid & 63, wave = tid >> 6;
  const int quad = lane >> 4, l15 = lane & 15;
  const int bh = blockIdx.x;
  const int qt = 31 - blockIdx.y;      // heavy blocks dispatched first

  const ushort* qb = Q + ((size_t)bh * S_ + qt * 64 + wave * 16 + l15) * HD_;
  bf8_t qf[8];
#pragma unroll
  for (int c = 0; c < 8; ++c)
    qf[c] = *(const bf8_t*)(qb + c * 32 + quad * 8);

  bf8_t onef;
#pragma unroll
  for (int j = 0; j < 8; ++j) onef[j] = (short)0x3f80;   // 1.0 bf16

  f4_t o[16];
#pragma unroll
  for (int i = 0; i < 16; ++i) o[i] = (f4_t){0.f, 0.f, 0.f, 0.f};
  f4_t ol = (f4_t){0.f, 0.f, 0.f, 0.f};                 // l accumulator
  float m_r[4] = {-1e30f, -1e30f, -1e30f, -1e30f};

  const int qrow0 = qt * 64 + wave * 16 + quad * 4;
  const int wave_min_row = qt * 64 + wave * 16;
  const int nkt = 2 * (qt + 1);
  const ushort* kb0 = K + (size_t)bh * S_ * HD_;
  const ushort* vb0 = VT + (size_t)bh * HD_ * S_;

  // staging indices (K): chunk c covers rows c*2..c*2+1 (512B each)
  const int st_row_off = lane >> 5;    // 0/1
  const int st_u = lane & 31;

  for (int kt = 0; kt < nkt; ++kt) {
    const int key0 = kt * 32;
    __syncthreads();
    // K: global_load_lds, 16B-chunk XOR swizzle in the GLOBAL address
#pragma unroll
    for (int i = 0; i < 4; ++i) {
      const int c = wave * 4 + i;
      const int row = c * 2 + st_row_off;
      const int g = st_u ^ (row & 7);
      gload16(kb0 + (size_t)(key0 + row) * HD_ + g * 8, &Kls[c * 512]);
    }
    // V: VGPR roundtrip staging
#pragma unroll
    for (int i = 0; i < 4; ++i) {
      const int u = tid + 256 * i;
      const int d = u >> 2, cu = u & 3;
      *(uint4*)(&Vls[d][cu * 8]) =
          *(const uint4*)(vb0 + (size_t)d * S_ + key0 + cu * 8);
    }
    __syncthreads();

    // S = Q K^T : 16 x 32 (swizzled Kls reads)
    f4_t sf0 = (f4_t){0.f, 0.f, 0.f, 0.f};
    f4_t sf1 = (f4_t){0.f, 0.f, 0.f, 0.f};
    const int sx = l15 & 7;
#pragma unroll
    for (int cc = 0; cc < 8; ++cc) {
      const int w = cc * 4 + quad;
      const bf8_t b0 = *(const bf8_t*)(&Kls[l15 * 256 + (w ^ sx) * 8]);
      const bf8_t b1 = *(const bf8_t*)(&Kls[(16 + l15) * 256 + (w ^ sx) * 8]);
      sf0 = MFMA16(qf[cc], b0, sf0);
      sf1 = MFMA16(qf[cc], b1, sf1);
    }

    // mask (only when tile crosses the diagonal for this wave)
    float mt[4];
    if (key0 + 31 <= wave_min_row) {
#pragma unroll
      for (int r = 0; r < 4; ++r) mt[r] = fmaxf(sf0[r], sf1[r]);
    } else {
#pragma unroll
      for (int r = 0; r < 4; ++r) {
        const int qr = qrow0 + r;
        sf0[r] = (key0 + l15 <= qr)      ? sf0[r] : -1e30f;
        sf1[r] = (key0 + 16 + l15 <= qr) ? sf1[r] : -1e30f;
        mt[r] = fmaxf(sf0[r], sf1[r]);
      }
    }
#pragma unroll
    for (int off = 1; off < 16; off <<= 1)
#pragma unroll
      for (int r = 0; r < 4; ++r)
        mt[r] = fmaxf(mt[r], __shfl_xor(mt[r], off));

    // rescale only when the running max grew (rare)
    const bool chg = (mt[0] > m_r[0]) | (mt[1] > m_r[1]) |
                     (mt[2] > m_r[2]) | (mt[3] > m_r[3]);
    if (__any(chg)) {
      float alpha[4];
#pragma unroll
      for (int r = 0; r < 4; ++r) {
        const float mn = fmaxf(m_r[r], mt[r]);
        alpha[r] = __expf(m_r[r] - mn);
        m_r[r] = mn;
      }
#pragma unroll
      for (int i = 0; i < 16; ++i)
#pragma unroll
        for (int r = 0; r < 4; ++r)
          o[i][r] *= alpha[r];
#pragma unroll
      for (int r = 0; r < 4; ++r) ol[r] *= alpha[r];
    }
#pragma unroll
    for (int r = 0; r < 4; ++r) {
      sf0[r] = __expf(sf0[r] - m_r[r]);
      sf1[r] = __expf(sf1[r] - m_r[r]);
    }

    // P (C-layout) -> LDS -> A-layout; wave-private
#pragma unroll
    for (int r = 0; r < 4; ++r) {
      Pls[wave][quad * 4 + r][l15]      = f2bf(sf0[r]);
      Pls[wave][quad * 4 + r][16 + l15] = f2bf(sf1[r]);
    }
    const bf8_t ap = *(const bf8_t*)(&Pls[wave][l15][quad * 8]);

    // O += P V ; l += P 1
    ol = MFMA16(ap, onef, ol);
#pragma unroll
    for (int df = 0; df < 16; ++df) {
      const bf8_t bv = *(const bf8_t*)(&Vls[df * 16 + l15][quad * 8]);
      o[df] = MFMA16(ap, bv, o[df]);
    }
  }

  // epilogue: attn (B,S,D) bf16
  const int b = bh >> 4, h = bh & 15;
  float inv[4];
#pragma unroll
  for (int r = 0; r < 4; ++r) inv[r] = 1.0f / ol[r];
#pragma unroll
  for (int r = 0; r < 4; ++r) {
    const int s = qt * 64 + wave * 16 + quad * 4 + r;
    ushort* prow = attn + ((size_t)b * S_ + s) * D_ + h * HD_ + l15;
#pragma unroll
    for (int df = 0; df < 16; ++df)
      prow[df * 16] = f2bf(o[df][r] * inv[r]);
  }
}

// ---------------------------------------------------------------------------
// FALLBACK (dequant-in-GEMM), used only if ws < 256 MiB
// ---------------------------------------------------------------------------
__global__ __launch_bounds__(256) void gemm_qkv_fb(
    const float* __restrict__ hid, const int* __restrict__ qw,
    const int* __restrict__ qz, const float* __restrict__ sc,
    ushort* __restrict__ wq, ushort* __restrict__ wk, ushort* __restrict__ wv)
{
  __shared__ ushort As_[128][72];
  __shared__ ushort Bs_[128][72];
  const int tid  = threadIdx.x;
  const int lane = tid & 63, wave = tid >> 6;
  const int quad = lane >> 4, l15 = lane & 15;
  const int n0 = blockIdx.x * 128, m0 = blockIdx.y * 128;
  f4_t acc[4][4];
#pragma unroll
  for (int i = 0; i < 4; ++i)
#pragma unroll
    for (int j = 0; j < 4; ++j) acc[i][j] = (f4_t){0.f, 0.f, 0.f, 0.f};
  const int bn  = tid & 127;
  const int brh = tid >> 7;
  const int gn  = n0 + bn;
  const int wm = (wave >> 1) * 64, wn = (wave & 1) * 64;
  for (int k0 = 0; k0 < D_; k0 += 64) {
#pragma unroll
    for (int i = 0; i < 8; ++i) {
      const int u = tid + 256 * i;
      const int m = u >> 4, kc = u & 15;
      const float4 v = *(const float4*)(hid + (size_t)(m0 + m) * D_ + k0 + kc * 4);
      ushort4 b;
      b.x = f2bf(v.x); b.y = f2bf(v.y); b.z = f2bf(v.z); b.w = f2bf(v.w);
      *(ushort4*)(&As_[m][kc * 4]) = b;
    }
    {
      const int g = k0 >> 7;
      const int zw = qz[g * (N1 / 8) + (gn >> 3)];
      const float zp = (float)(((zw >> ((gn & 7) * 4)) & 15) + 1);
      const float scale = sc[g * N1 + gn];
      const float szp = scale * zp;
      const int kq0 = (k0 >> 3) + brh * 4;
#pragma unroll
      for (int i = 0; i < 4; ++i) {
        const uint w = (uint)qw[(size_t)(kq0 + i) * N1 + gn];
        us8_t pk;
#pragma unroll
        for (int j = 0; j < 8; ++j)
          pk[j] = f2bf(fmaf((float)((w >> (4 * j)) & 15u), scale, -szp));
        *(us8_t*)(&Bs_[bn][(brh * 4 + i) * 8]) = pk;
      }
    }
    __syncthreads();
#pragma unroll
    for (int kk = 0; kk < 64; kk += 32) {
      bf8_t af[4], bfv[4];
#pragma unroll
      for (int i = 0; i < 4; ++i)
        af[i] = *(const bf8_t*)(&As_[wm + i * 16 + l15][kk + quad * 8]);
#pragma unroll
      for (int j = 0; j < 4; ++j)
        bfv[j] = *(const bf8_t*)(&Bs_[wn + j * 16 + l15][kk + quad * 8]);
#pragma unroll
      for (int i = 0; i < 4; ++i)
#pragma unroll
        for (int j = 0; j < 4; ++j)
          acc[i][j] = MFMA16(af[i], bfv[j], acc[i][j]);
    }
    __syncthreads();
  }
  const int which = n0 >> 12;
  const int nh = (n0 & 4095) >> 8;
  const int d0 = n0 & 255;
  const int bb = m0 >> 11;
  const int s_base = m0 & 2047;
  ushort* dst = (which == 0) ? wq : (which == 1) ? wk : wv;
  const float osc = (which == 0) ? 0.0625f : 1.0f;
  const size_t rowbase = ((size_t)bb * H_ + nh) * S_;
#pragma unroll
  for (int i = 0; i < 4; ++i) {
#pragma unroll
    for (int r = 0; r < 4; ++r) {
      const int s = s_base + wm + i * 16 + quad * 4 + r;
      ushort* prow = dst + (rowbase + s) * HD_ + d0 + wn + l15;
#pragma unroll
      for (int j = 0; j < 4; ++j)
        prow[j * 16] = f2bf(acc[i][j][r] * osc);
    }
  }
}

__global__ __launch_bounds__(256) void gemm_out_fb(
    const ushort* __restrict__ attn, const int* __restrict__ qw,
    const int* __restrict__ qz, const float* __restrict__ sc,
    float* __restrict__ out)
{
  __shared__ ushort As_[128][72];
  __shared__ ushort Bs_[128][72];
  const int tid  = threadIdx.x;
  const int lane = tid & 63, wave = tid >> 6;
  const int quad = lane >> 4, l15 = lane & 15;
  const int n0 = blockIdx.x * 128, m0 = blockIdx.y * 128;
  f4_t acc[4][4];
#pragma unroll
  for (int i = 0; i < 4; ++i)
#pragma unroll
    for (int j = 0; j < 4; ++j) acc[i][j] = (f4_t){0.f, 0.f, 0.f, 0.f};
  const int bn  = tid & 127;
  const int brh = tid >> 7;
  const int gn  = n0 + bn;
  const int wm = (wave >> 1) * 64, wn = (wave & 1) * 64;
  for (int k0 = 0; k0 < D_; k0 += 64) {
#pragma unroll
    for (int i = 0; i < 4; ++i) {
      const int u = tid + 256 * i;
      const int m = u >> 3, kc = u & 7;
      *(uint4*)(&As_[m][kc * 8]) =
          *(const uint4*)(attn + (size_t)(m0 + m) * D_ + k0 + kc * 8);
    }
    {
      const int g = k0 >> 7;
      const int zw = qz[g * (N2 / 8) + (gn >> 3)];
      const float zp = (float)(((zw >> ((gn & 7) * 4)) & 15) + 1);
      const float scale = sc[g * N2 + gn];
      const float szp = scale * zp;
      const int kq0 = (k0 >> 3) + brh * 4;
#pragma unroll
      for (int i = 0; i < 4; ++i) {
        const uint w = (uint)qw[(size_t)(kq0 + i) * N2 + gn];
        us8_t pk;
#pragma unroll
        for (int j = 0; j < 8; ++j)
          pk[j] = f2bf(fmaf((float)((w >> (4 * j)) & 15u), scale, -szp));
        *(us8_t*)(&Bs_[bn][(brh * 4 + i) * 8]) = pk;
      }
    }
    __syncthreads();
#pragma unroll
    for (int kk = 0; kk < 64; kk += 32) {
      bf8_t af[4], bfv[4];
#pragma unroll
      for (int i = 0; i < 4; ++i)
        af[i] = *(const bf8_t*)(&As_[wm + i * 16 + l15][kk + quad * 8]);
#pragma unroll
      for (int j = 0; j < 4; ++j)
        bfv[j] = *(const bf8_t*)(&Bs_[wn + j * 16 + l15][kk + quad * 8]);
#pragma unroll
      for (int i = 0; i < 4; ++i)
#pragma unroll
        for (int j = 0; j < 4; ++j)
          acc[i][j] = MFMA16(af[i], bfv[j], acc[i][j]);
    }
    __syncthreads();
  }
#pragma unroll
  for (int i = 0; i < 4; ++i) {
#pragma unroll
    for (int r = 0; r < 4; ++r) {
      float* prow = out + (size_t)(m0 + wm + i * 16 + quad * 4 + r) * D_ + n0 + wn + l15;
#pragma unroll
      for (int j = 0; j < 4; ++j)
        prow[j * 16] = acc[i][j][r];
    }
  }
}

// ---------------------------------------------------------------------------
extern "C" void kernel_launch(void* const* d_in, const int* in_sizes, int n_in,
                              void* d_out, int out_size, void* d_ws, size_t ws_size,
                              hipStream_t stream)
{
  const float* hid    = (const float*)d_in[0];
  const int*   qw_qkv = (const int*)d_in[1];
  const int*   qz_qkv = (const int*)d_in[2];
  const float* sc_qkv = (const float*)d_in[3];
  const int*   qw_out = (const int*)d_in[4];
  const int*   qz_out = (const int*)d_in[5];
  const float* sc_out = (const float*)d_in[6];
  float* out = (float*)d_out;

  const size_t QKV_E = (size_t)B_ * H_ * S_ * HD_;   // 16,777,216 elems

  if (ws_size >= (size_t)268435456) {
    // fast path: exactly 256 MiB layout
    ushort* hidA  = (ushort*)d_ws;          // 33.5 MB (aliased by attn later)
    ushort* wsq   = hidA + QKV_E;
    ushort* wsk   = wsq + QKV_E;
    ushort* wsv   = wsk + QKV_E;
    ushort* wsvt  = wsv + QKV_E;
    ushort* wT    = wsvt + QKV_E;           // 100.7 MB (Wqkv^T, then Wout^T)
    ushort* wsattn = hidA;                  // alias: hidA dead after gemm_fast_qkv

    cvt_bf16<<<dim3(8192), 256, 0, stream>>>(hid, hidA);
    dequant_w<<<dim3(192, 64), 256, 0, stream>>>(qw_qkv, qz_qkv, sc_qkv, wT, N1);
    gemm_fast_qkv<<<dim3(48, 16), 512, 0, stream>>>(hidA, wT, wsq, wsk, wsv);
    rope_qk<<<dim3(16384), 256, 0, stream>>>(wsq, wsk);
    transpose_v<<<dim3(32, 4, 32), 256, 0, stream>>>(wsv, wsvt);
    flash_attn2<<<dim3(32, 32), 256, 0, stream>>>(wsq, wsk, wsvt, wsattn);
    dequant_w<<<dim3(64, 64), 256, 0, stream>>>(qw_out, qz_out, sc_out, wT, N2);
    gemm_fast_out<<<dim3(16, 16), 512, 0, stream>>>(wsattn, wT, out);
  } else {
    // fallback path (168 MB)
    ushort* wsq    = (ushort*)d_ws;
    ushort* wsk    = wsq + QKV_E;
    ushort* wsv    = wsk + QKV_E;
    ushort* wsvt   = wsv + QKV_E;
    ushort* wsattn = wsvt + QKV_E;

    gemm_qkv_fb<<<dim3(96, 32), 256, 0, stream>>>(hid, qw_qkv, qz_qkv, sc_qkv, wsq, wsk, wsv);
    rope_qk<<<dim3(16384), 256, 0, stream>>>(wsq, wsk);
    transpose_v<<<dim3(32, 4, 32), 256, 0, stream>>>(wsv, wsvt);
    flash_attn2<<<dim3(32, 32), 256, 0, stream>>>(wsq, wsk, wsvt, wsattn);
    gemm_out_fb<<<dim3(32, 32), 256, 0, stream>>>(wsattn, qw_out, qz_out, sc_out, out);
  }
}

// Round 2
// 950.500 us; speedup vs baseline: 1.0084x; 1.0084x over previous
//
#include <hip/hip_runtime.h>

#define B_  2
#define S_  2048
#define D_  4096
#define H_  16
#define HD_ 256
#define N1  12288
#define N2  4096

typedef __attribute__((ext_vector_type(8))) short  bf8_t;   // 8 bf16 (4 VGPRs)
typedef __attribute__((ext_vector_type(8))) ushort us8_t;
typedef __attribute__((ext_vector_type(4))) float  f4_t;

__device__ __forceinline__ ushort f2bf(float f) {
  union { float f; uint u; } c; c.f = f;
  uint u = c.u;
  return (ushort)((u + 0x7fffu + ((u >> 16) & 1u)) >> 16);  // RNE
}
__device__ __forceinline__ float bf2f(ushort b) {
  union { uint u; float f; } c; c.u = ((uint)b) << 16;
  return c.f;
}

#define MFMA16(a, b, c) __builtin_amdgcn_mfma_f32_16x16x32_bf16((a), (b), (c), 0, 0, 0)

__device__ __forceinline__ void gload16(const void* g, void* l) {
  __builtin_amdgcn_global_load_lds(
      (const __attribute__((address_space(1))) void*)g,
      (__attribute__((address_space(3))) void*)l, 16, 0, 0);
}

// ---------------------------------------------------------------------------
// hidden f32 -> bf16
// ---------------------------------------------------------------------------
__global__ __launch_bounds__(256) void cvt_bf16(const float* __restrict__ x,
                                                ushort* __restrict__ y)
{
  const size_t i = ((size_t)blockIdx.x * 256 + threadIdx.x) * 8;
  const float4 a = *(const float4*)(x + i);
  const float4 b = *(const float4*)(x + i + 4);
  us8_t o;
  o[0] = f2bf(a.x); o[1] = f2bf(a.y); o[2] = f2bf(a.z); o[3] = f2bf(a.w);
  o[4] = f2bf(b.x); o[5] = f2bf(b.y); o[6] = f2bf(b.z); o[7] = f2bf(b.w);
  *(us8_t*)(y + i) = o;
}

// ---------------------------------------------------------------------------
// GPTQ dequant -> W^T bf16 [N][4096]  (one-shot, memory-bound)
// ---------------------------------------------------------------------------
__global__ __launch_bounds__(256) void dequant_w(
    const int* __restrict__ qw, const int* __restrict__ qz,
    const float* __restrict__ sc, ushort* __restrict__ wt, const int N)
{
  __shared__ ushort T[64][72];
  const int tid = threadIdx.x;
  const int n0 = blockIdx.x * 64, k0 = blockIdx.y * 64;
  const int g = k0 >> 7;                           // GS=128
  const int nn  = tid & 63;
  const int kw0 = tid >> 6;                        // 0..3
  const int gn = n0 + nn;
  const int zw = qz[g * (N >> 3) + (gn >> 3)];
  const float zp = (float)(((zw >> ((gn & 7) * 4)) & 15) + 1);
  const float scale = sc[g * N + gn];
  const float szp = scale * zp;
#pragma unroll
  for (int t = 0; t < 2; ++t) {
    const int kw = kw0 + t * 4;
    const uint w = (uint)qw[(size_t)((k0 >> 3) + kw) * N + gn];
    us8_t pk;
#pragma unroll
    for (int j = 0; j < 8; ++j)
      pk[j] = f2bf(fmaf((float)((w >> (4 * j)) & 15u), scale, -szp));
    *(us8_t*)(&T[nn][kw * 8]) = pk;
  }
  __syncthreads();
#pragma unroll
  for (int t = 0; t < 2; ++t) {
    const int u = tid + t * 256;
    const int r = u >> 3, c = u & 7;
    *(uint4*)(wt + (size_t)(n0 + r) * 4096 + k0 + c * 8) = *(uint4*)(&T[r][c * 8]);
  }
}

// ---------------------------------------------------------------------------
// 256x256 bf16 GEMM core, 8-phase-style schedule (T3+T4+T5).
//
// Geometry: BM=BN=256, BK=32, 8 waves (2M x 4N), wave tile 128x64,
// 4-deep circular LDS buffer (128 KiB), stage 3 tiles ahead.
//
// Each K-tile = TWO phases at m201's phase rate (16 MFMA + 4-8 ds_read +
// 2 global_load_lds per phase, double-barrier per phase):
//   P0: read af[0..3],bfv[0..3] | stage A-halves(t+3) | BAR | lgkm0 |
//       setprio1 | 16 MFMA (i=0..3) | setprio0 | BAR
//   P1: read af[4..7]           | stage B-halves(t+3) | BAR | lgkm0 |
//       setprio1 | 16 MFMA (i=4..7) | setprio0 | vmcnt(8) | BAR
// vmcnt never drains to 0 in the main loop; tail peels 8->4->0.
// Invariant: at end of tile t, outstanding = t+1(4),t+2(4),t+3(4)=12;
// vmcnt(8) retires tile t+1 -> ready for tile t+1's P0 reads.
// LDS swizzle: slot s of 128B row-pair p holds global 16B chunk s^(p&7),
// applied on BOTH the pre-swizzled global source and the ds_read offsets.
// ---------------------------------------------------------------------------
#define NT_ 128   /* 4096 / 32 */

#define STAGE_A(t_) do {                                                      \
    const int b_  = (t_) & 3;                                                 \
    const int kk_ = (t_) << 5;                                                \
    gload16(Arow0 + kk_,                      &As[b_][wave * 512]);           \
    gload16(Arow0 + (size_t)128 * 4096 + kk_, &As[b_][4096 + wave * 512]);    \
  } while (0)

#define STAGE_B(t_) do {                                                      \
    const int b_  = (t_) & 3;                                                 \
    const int kk_ = (t_) << 5;                                                \
    gload16(Brow0 + kk_,                      &Bs[b_][wave * 512]);           \
    gload16(Brow0 + (size_t)128 * 4096 + kk_, &Bs[b_][4096 + wave * 512]);    \
  } while (0)

#define NOSTAGE do { } while (0)

#define VMW(n_) asm volatile("s_waitcnt vmcnt(" #n_ ")" ::: "memory")
#define NOVMW   do { } while (0)

#define PHASE0(t_, STAGE_) do {                                               \
    const char* ab_ = (const char*)(&As[(t_) & 3][0]);                        \
    const char* bb_ = (const char*)(&Bs[(t_) & 3][0]);                        \
    _Pragma("unroll") for (int i = 0; i < 4; ++i)                             \
        af[i] = *(const bf8_t*)(ab_ + aoff[i]);                               \
    _Pragma("unroll") for (int j = 0; j < 4; ++j)                             \
        bfv[j] = *(const bf8_t*)(bb_ + boff[j]);                              \
    STAGE_;                                                                   \
    __builtin_amdgcn_s_barrier();                                             \
    asm volatile("s_waitcnt lgkmcnt(0)" ::: "memory");                        \
    __builtin_amdgcn_sched_barrier(0);                                        \
    __builtin_amdgcn_s_setprio(1);                                            \
    _Pragma("unroll") for (int i = 0; i < 4; ++i)                             \
    _Pragma("unroll") for (int j = 0; j < 4; ++j)                             \
        acc[i][j] = MFMA16(af[i], bfv[j], acc[i][j]);                         \
    __builtin_amdgcn_s_setprio(0);                                            \
    __builtin_amdgcn_sched_barrier(0);                                        \
    __builtin_amdgcn_s_barrier();                                             \
  } while (0)

#define PHASE1(t_, STAGE_, VMWAIT_) do {                                      \
    const char* ab_ = (const char*)(&As[(t_) & 3][0]);                        \
    _Pragma("unroll") for (int i = 0; i < 4; ++i)                             \
        af[4 + i] = *(const bf8_t*)(ab_ + aoff[4 + i]);                       \
    STAGE_;                                                                   \
    __builtin_amdgcn_s_barrier();                                             \
    asm volatile("s_waitcnt lgkmcnt(0)" ::: "memory");                        \
    __builtin_amdgcn_sched_barrier(0);                                        \
    __builtin_amdgcn_s_setprio(1);                                            \
    _Pragma("unroll") for (int i = 0; i < 4; ++i)                             \
    _Pragma("unroll") for (int j = 0; j < 4; ++j)                             \
        acc[4 + i][j] = MFMA16(af[4 + i], bfv[j], acc[4 + i][j]);             \
    __builtin_amdgcn_s_setprio(0);                                            \
    __builtin_amdgcn_sched_barrier(0);                                        \
    VMWAIT_;                                                                  \
    __builtin_amdgcn_s_barrier();                                             \
  } while (0)

#define GEMM256_CORE(Ag_, Bg_)                                                \
  __shared__ ushort As[4][8192];                                              \
  __shared__ ushort Bs[4][8192];                                              \
  const int tid  = threadIdx.x;                                               \
  const int lane = tid & 63, wave = tid >> 6;                                 \
  const int quad = lane >> 4, l15 = lane & 15;                                \
  const int wm = wave >> 2, wn = wave & 3;                                    \
  const int gx = gridDim.x;                                                   \
  int lin = blockIdx.y * gx + blockIdx.x;                                     \
  lin = (lin & 7) * (gx << 1) + (lin >> 3); /* bijective: nwg = gx*16, %8==0 */\
  const int n0 = (lin >> 4) << 8;                                             \
  const int m0 = (lin & 15) << 8;                                             \
  f4_t acc[8][4];                                                             \
  _Pragma("unroll") for (int i = 0; i < 8; ++i)                               \
  _Pragma("unroll") for (int j = 0; j < 4; ++j)                               \
      acc[i][j] = (f4_t){0.f, 0.f, 0.f, 0.f};                                 \
  /* staging: linear chunk q = rr*512 + tid; p=q>>3 (128B pair), s=q&7 */     \
  const int pq   = tid >> 3;                                                  \
  const int gch  = (tid & 7) ^ (pq & 7);                                      \
  const int grow = 2 * pq + (gch >> 2);                                       \
  const int gcol = (gch & 3) * 8;                                             \
  const ushort* Arow0 = Ag_ + (size_t)(m0 + grow) * 4096 + gcol;              \
  const ushort* Brow0 = Bg_ + (size_t)(n0 + grow) * 4096 + gcol;              \
  /* ds_read offsets: row R -> pair p=R>>1, slot ((R&1)*4+quad)^(p&7) */      \
  const int h_ = l15 >> 1;                                                    \
  const int sx = ((l15 & 1) * 4 + quad) ^ h_;                                 \
  int aoff[8], boff[4];                                                       \
  _Pragma("unroll") for (int i = 0; i < 8; ++i)                               \
      aoff[i] = (((wm * 64 + i * 8 + h_) * 8) + sx) * 16;                     \
  _Pragma("unroll") for (int j = 0; j < 4; ++j)                               \
      boff[j] = (((wn * 32 + j * 8 + h_) * 8) + sx) * 16;                     \
  bf8_t af[8], bfv[4];                                                        \
  STAGE_A(0); STAGE_B(0);                                                     \
  STAGE_A(1); STAGE_B(1);                                                     \
  STAGE_A(2); STAGE_B(2);                                                     \
  VMW(8);                                                                     \
  __builtin_amdgcn_s_barrier();                                               \
  for (int t = 0; t < NT_ - 3; ++t) {                                         \
    PHASE0(t, STAGE_A(t + 3));                                                \
    PHASE1(t, STAGE_B(t + 3), VMW(8));                                        \
  }                                                                           \
  PHASE0(NT_ - 3, NOSTAGE);                                                   \
  PHASE1(NT_ - 3, NOSTAGE, VMW(4));                                           \
  PHASE0(NT_ - 2, NOSTAGE);                                                   \
  PHASE1(NT_ - 2, NOSTAGE, VMW(0));                                           \
  PHASE0(NT_ - 1, NOSTAGE);                                                   \
  PHASE1(NT_ - 1, NOSTAGE, NOVMW);

__global__ __launch_bounds__(512, 2) void gemm_fast_qkv(
    const ushort* __restrict__ A, const ushort* __restrict__ BT,
    ushort* __restrict__ wq, ushort* __restrict__ wk, ushort* __restrict__ wv)
{
  GEMM256_CORE(A, BT)
  // epilogue: scatter to (which, B, H, S, hd) bf16; q prescaled by 1/sqrt(hd)
  // n0 is a multiple of 256 -> tile covers exactly one head's 256 dims.
  const int which = n0 >> 12;
  const int nh = (n0 & 4095) >> 8;
  const int bb = m0 >> 11;
  const int s_base = m0 & 2047;
  ushort* dst = (which == 0) ? wq : (which == 1) ? wk : wv;
  const float osc = (which == 0) ? 0.0625f : 1.0f;
  const size_t rowbase = ((size_t)bb * H_ + nh) * S_;
#pragma unroll
  for (int i = 0; i < 8; ++i) {
#pragma unroll
    for (int r = 0; r < 4; ++r) {
      const int s = s_base + wm * 128 + i * 16 + quad * 4 + r;
      ushort* prow = dst + (rowbase + s) * HD_ + wn * 64 + l15;
#pragma unroll
      for (int j = 0; j < 4; ++j)
        prow[j * 16] = f2bf(acc[i][j][r] * osc);
    }
  }
}

__global__ __launch_bounds__(512, 2) void gemm_fast_out(
    const ushort* __restrict__ A, const ushort* __restrict__ BT,
    float* __restrict__ out)
{
  GEMM256_CORE(A, BT)
#pragma unroll
  for (int i = 0; i < 8; ++i) {
#pragma unroll
    for (int r = 0; r < 4; ++r) {
      float* prow = out + (size_t)(m0 + wm * 128 + i * 16 + quad * 4 + r) * D_
                        + n0 + wn * 64 + l15;
#pragma unroll
      for (int j = 0; j < 4; ++j)
        prow[j * 16] = acc[i][j][r];
    }
  }
}

// ---------------------------------------------------------------------------
// RoPE in-place on q and k (q is prescaled; rotation commutes with scalar)
// ---------------------------------------------------------------------------
__global__ __launch_bounds__(256) void rope_qk(ushort* __restrict__ q, ushort* __restrict__ k)
{
  const int idx = blockIdx.x * 256 + threadIdx.x;
  const int i   = idx & 31;
  const int row = (idx >> 5) & 0xFFFF;
  const int buf = idx >> 21;
  const int s   = row & 2047;
  ushort* p = (buf ? k : q) + (size_t)row * HD_ + 2 * i;
  const float inv_freq = expf((float)(2 * i) * -0.14391157f);
  const float ang = (float)s * inv_freq;
  float sn, cs;
  sincosf(ang, &sn, &cs);
  uint pr = *(uint*)p;
  const float x1 = bf2f((ushort)(pr & 0xFFFF));
  const float x2 = bf2f((ushort)(pr >> 16));
  const uint lo = f2bf(x1 * cs - x2 * sn);
  const uint hi = f2bf(x2 * cs + x1 * sn);
  *(uint*)p = lo | (hi << 16);
}

// ---------------------------------------------------------------------------
// V (B,H,S,hd) -> VT (B,H,hd,S)
// ---------------------------------------------------------------------------
__global__ __launch_bounds__(256) void transpose_v(const ushort* __restrict__ v,
                                                   ushort* __restrict__ vt)
{
  __shared__ uint t32[64][65];
  const int tid = threadIdx.x;
  const int s0 = blockIdx.x * 64, d0 = blockIdx.y * 64, bh = blockIdx.z;
  const ushort* src = v + ((size_t)bh * S_ + s0) * HD_ + d0;
#pragma unroll
  for (int i = 0; i < 2; ++i) {
    const int u = tid + 256 * i;
    const int r = u >> 3, cu = u & 7;
    const uint4 val = *(const uint4*)(src + (size_t)r * HD_ + cu * 8);
    const ushort* pv = (const ushort*)&val;
#pragma unroll
    for (int j = 0; j < 8; ++j) t32[r][cu * 8 + j] = pv[j];
  }
  __syncthreads();
  ushort* dstb = vt + ((size_t)bh * HD_ + d0) * S_ + s0;
#pragma unroll
  for (int i = 0; i < 2; ++i) {
    const int u = tid + 256 * i;
    const int dr = u >> 3, cu = u & 7;
    union { ushort u16[8]; uint4 v4; } tmp;
#pragma unroll
    for (int j = 0; j < 8; ++j) tmp.u16[j] = (ushort)t32[cu * 8 + j][dr];
    *(uint4*)(dstb + (size_t)dr * S_ + cu * 8) = tmp.v4;
  }
}

// ---------------------------------------------------------------------------
// Flash attention v2: ones-column l, rescale-skip, swizzled global_load_lds K
// Q is prescaled by 1/sqrt(hd). Grid: (bh, qtile) with qtile heavy-first.
// ---------------------------------------------------------------------------
__global__ __launch_bounds__(256) void flash_attn2(
    const ushort* __restrict__ Q, const ushort* __restrict__ K,
    const ushort* __restrict__ VT, ushort* __restrict__ attn)
{
  __shared__ ushort Kls[8192];         // 32 keys x 256 c, 16B-chunk swizzled
  __shared__ ushort Vls[256][40];      // [d][key] +8 pad
  __shared__ ushort Pls[4][16][40];    // per-wave P roundtrip
  const int tid  = threadIdx.x;
  const int lane = tid & 63, wave = tid >> 6;
  const int quad = lane >> 4, l15 = lane & 15;
  const int bh = blockIdx.x;
  const int qt = 31 - blockIdx.y;      // heavy blocks dispatched first

  const ushort* qb = Q + ((size_t)bh * S_ + qt * 64 + wave * 16 + l15) * HD_;
  bf8_t qf[8];
#pragma unroll
  for (int c = 0; c < 8; ++c)
    qf[c] = *(const bf8_t*)(qb + c * 32 + quad * 8);

  bf8_t onef;
#pragma unroll
  for (int j = 0; j < 8; ++j) onef[j] = (short)0x3f80;   // 1.0 bf16

  f4_t o[16];
#pragma unroll
  for (int i = 0; i < 16; ++i) o[i] = (f4_t){0.f, 0.f, 0.f, 0.f};
  f4_t ol = (f4_t){0.f, 0.f, 0.f, 0.f};                 // l accumulator
  float m_r[4] = {-1e30f, -1e30f, -1e30f, -1e30f};

  const int qrow0 = qt * 64 + wave * 16 + quad * 4;
  const int wave_min_row = qt * 64 + wave * 16;
  const int nkt = 2 * (qt + 1);
  const ushort* kb0 = K + (size_t)bh * S_ * HD_;
  const ushort* vb0 = VT + (size_t)bh * HD_ * S_;

  // staging indices (K): chunk c covers rows c*2..c*2+1 (512B each)
  const int st_row_off = lane >> 5;    // 0/1
  const int st_u = lane & 31;

  for (int kt = 0; kt < nkt; ++kt) {
    const int key0 = kt * 32;
    __syncthreads();
    // K: global_load_lds, 16B-chunk XOR swizzle in the GLOBAL address
#pragma unroll
    for (int i = 0; i < 4; ++i) {
      const int c = wave * 4 + i;
      const int row = c * 2 + st_row_off;
      const int g = st_u ^ (row & 7);
      gload16(kb0 + (size_t)(key0 + row) * HD_ + g * 8, &Kls[c * 512]);
    }
    // V: VGPR roundtrip staging
#pragma unroll
    for (int i = 0; i < 4; ++i) {
      const int u = tid + 256 * i;
      const int d = u >> 2, cu = u & 3;
      *(uint4*)(&Vls[d][cu * 8]) =
          *(const uint4*)(vb0 + (size_t)d * S_ + key0 + cu * 8);
    }
    __syncthreads();

    // S = Q K^T : 16 x 32 (swizzled Kls reads)
    f4_t sf0 = (f4_t){0.f, 0.f, 0.f, 0.f};
    f4_t sf1 = (f4_t){0.f, 0.f, 0.f, 0.f};
    const int sx = l15 & 7;
#pragma unroll
    for (int cc = 0; cc < 8; ++cc) {
      const int w = cc * 4 + quad;
      const bf8_t b0 = *(const bf8_t*)(&Kls[l15 * 256 + (w ^ sx) * 8]);
      const bf8_t b1 = *(const bf8_t*)(&Kls[(16 + l15) * 256 + (w ^ sx) * 8]);
      sf0 = MFMA16(qf[cc], b0, sf0);
      sf1 = MFMA16(qf[cc], b1, sf1);
    }

    // mask (only when tile crosses the diagonal for this wave)
    float mt[4];
    if (key0 + 31 <= wave_min_row) {
#pragma unroll
      for (int r = 0; r < 4; ++r) mt[r] = fmaxf(sf0[r], sf1[r]);
    } else {
#pragma unroll
      for (int r = 0; r < 4; ++r) {
        const int qr = qrow0 + r;
        sf0[r] = (key0 + l15 <= qr)      ? sf0[r] : -1e30f;
        sf1[r] = (key0 + 16 + l15 <= qr) ? sf1[r] : -1e30f;
        mt[r] = fmaxf(sf0[r], sf1[r]);
      }
    }
#pragma unroll
    for (int off = 1; off < 16; off <<= 1)
#pragma unroll
      for (int r = 0; r < 4; ++r)
        mt[r] = fmaxf(mt[r], __shfl_xor(mt[r], off));

    // rescale only when the running max grew (rare)
    const bool chg = (mt[0] > m_r[0]) | (mt[1] > m_r[1]) |
                     (mt[2] > m_r[2]) | (mt[3] > m_r[3]);
    if (__any(chg)) {
      float alpha[4];
#pragma unroll
      for (int r = 0; r < 4; ++r) {
        const float mn = fmaxf(m_r[r], mt[r]);
        alpha[r] = __expf(m_r[r] - mn);
        m_r[r] = mn;
      }
#pragma unroll
      for (int i = 0; i < 16; ++i)
#pragma unroll
        for (int r = 0; r < 4; ++r)
          o[i][r] *= alpha[r];
#pragma unroll
      for (int r = 0; r < 4; ++r) ol[r] *= alpha[r];
    }
#pragma unroll
    for (int r = 0; r < 4; ++r) {
      sf0[r] = __expf(sf0[r] - m_r[r]);
      sf1[r] = __expf(sf1[r] - m_r[r]);
    }

    // P (C-layout) -> LDS -> A-layout; wave-private
#pragma unroll
    for (int r = 0; r < 4; ++r) {
      Pls[wave][quad * 4 + r][l15]      = f2bf(sf0[r]);
      Pls[wave][quad * 4 + r][16 + l15] = f2bf(sf1[r]);
    }
    const bf8_t ap = *(const bf8_t*)(&Pls[wave][l15][quad * 8]);

    // O += P V ; l += P 1
    ol = MFMA16(ap, onef, ol);
#pragma unroll
    for (int df = 0; df < 16; ++df) {
      const bf8_t bv = *(const bf8_t*)(&Vls[df * 16 + l15][quad * 8]);
      o[df] = MFMA16(ap, bv, o[df]);
    }
  }

  // epilogue: attn (B,S,D) bf16
  const int b = bh >> 4, h = bh & 15;
  float inv[4];
#pragma unroll
  for (int r = 0; r < 4; ++r) inv[r] = 1.0f / ol[r];
#pragma unroll
  for (int r = 0; r < 4; ++r) {
    const int s = qt * 64 + wave * 16 + quad * 4 + r;
    ushort* prow = attn + ((size_t)b * S_ + s) * D_ + h * HD_ + l15;
#pragma unroll
    for (int df = 0; df < 16; ++df)
      prow[df * 16] = f2bf(o[df][r] * inv[r]);
  }
}

// ---------------------------------------------------------------------------
// FALLBACK (dequant-in-GEMM), used only if ws < 256 MiB
// ---------------------------------------------------------------------------
__global__ __launch_bounds__(256) void gemm_qkv_fb(
    const float* __restrict__ hid, const int* __restrict__ qw,
    const int* __restrict__ qz, const float* __restrict__ sc,
    ushort* __restrict__ wq, ushort* __restrict__ wk, ushort* __restrict__ wv)
{
  __shared__ ushort As_[128][72];
  __shared__ ushort Bs_[128][72];
  const int tid  = threadIdx.x;
  const int lane = tid & 63, wave = tid >> 6;
  const int quad = lane >> 4, l15 = lane & 15;
  const int n0 = blockIdx.x * 128, m0 = blockIdx.y * 128;
  f4_t acc[4][4];
#pragma unroll
  for (int i = 0; i < 4; ++i)
#pragma unroll
    for (int j = 0; j < 4; ++j) acc[i][j] = (f4_t){0.f, 0.f, 0.f, 0.f};
  const int bn  = tid & 127;
  const int brh = tid >> 7;
  const int gn  = n0 + bn;
  const int wm = (wave >> 1) * 64, wn = (wave & 1) * 64;
  for (int k0 = 0; k0 < D_; k0 += 64) {
#pragma unroll
    for (int i = 0; i < 8; ++i) {
      const int u = tid + 256 * i;
      const int m = u >> 4, kc = u & 15;
      const float4 v = *(const float4*)(hid + (size_t)(m0 + m) * D_ + k0 + kc * 4);
      ushort4 b;
      b.x = f2bf(v.x); b.y = f2bf(v.y); b.z = f2bf(v.z); b.w = f2bf(v.w);
      *(ushort4*)(&As_[m][kc * 4]) = b;
    }
    {
      const int g = k0 >> 7;
      const int zw = qz[g * (N1 / 8) + (gn >> 3)];
      const float zp = (float)(((zw >> ((gn & 7) * 4)) & 15) + 1);
      const float scale = sc[g * N1 + gn];
      const float szp = scale * zp;
      const int kq0 = (k0 >> 3) + brh * 4;
#pragma unroll
      for (int i = 0; i < 4; ++i) {
        const uint w = (uint)qw[(size_t)(kq0 + i) * N1 + gn];
        us8_t pk;
#pragma unroll
        for (int j = 0; j < 8; ++j)
          pk[j] = f2bf(fmaf((float)((w >> (4 * j)) & 15u), scale, -szp));
        *(us8_t*)(&Bs_[bn][(brh * 4 + i) * 8]) = pk;
      }
    }
    __syncthreads();
#pragma unroll
    for (int kk = 0; kk < 64; kk += 32) {
      bf8_t af[4], bfv[4];
#pragma unroll
      for (int i = 0; i < 4; ++i)
        af[i] = *(const bf8_t*)(&As_[wm + i * 16 + l15][kk + quad * 8]);
#pragma unroll
      for (int j = 0; j < 4; ++j)
        bfv[j] = *(const bf8_t*)(&Bs_[wn + j * 16 + l15][kk + quad * 8]);
#pragma unroll
      for (int i = 0; i < 4; ++i)
#pragma unroll
        for (int j = 0; j < 4; ++j)
          acc[i][j] = MFMA16(af[i], bfv[j], acc[i][j]);
    }
    __syncthreads();
  }
  const int which = n0 >> 12;
  const int nh = (n0 & 4095) >> 8;
  const int d0 = n0 & 255;
  const int bb = m0 >> 11;
  const int s_base = m0 & 2047;
  ushort* dst = (which == 0) ? wq : (which == 1) ? wk : wv;
  const float osc = (which == 0) ? 0.0625f : 1.0f;
  const size_t rowbase = ((size_t)bb * H_ + nh) * S_;
#pragma unroll
  for (int i = 0; i < 4; ++i) {
#pragma unroll
    for (int r = 0; r < 4; ++r) {
      const int s = s_base + wm + i * 16 + quad * 4 + r;
      ushort* prow = dst + (rowbase + s) * HD_ + d0 + wn + l15;
#pragma unroll
      for (int j = 0; j < 4; ++j)
        prow[j * 16] = f2bf(acc[i][j][r] * osc);
    }
  }
}

__global__ __launch_bounds__(256) void gemm_out_fb(
    const ushort* __restrict__ attn, const int* __restrict__ qw,
    const int* __restrict__ qz, const float* __restrict__ sc,
    float* __restrict__ out)
{
  __shared__ ushort As_[128][72];
  __shared__ ushort Bs_[128][72];
  const int tid  = threadIdx.x;
  const int lane = tid & 63, wave = tid >> 6;
  const int quad = lane >> 4, l15 = lane & 15;
  const int n0 = blockIdx.x * 128, m0 = blockIdx.y * 128;
  f4_t acc[4][4];
#pragma unroll
  for (int i = 0; i < 4; ++i)
#pragma unroll
    for (int j = 0; j < 4; ++j) acc[i][j] = (f4_t){0.f, 0.f, 0.f, 0.f};
  const int bn  = tid & 127;
  const int brh = tid >> 7;
  const int gn  = n0 + bn;
  const int wm = (wave >> 1) * 64, wn = (wave & 1) * 64;
  for (int k0 = 0; k0 < D_; k0 += 64) {
#pragma unroll
    for (int i = 0; i < 4; ++i) {
      const int u = tid + 256 * i;
      const int m = u >> 3, kc = u & 7;
      *(uint4*)(&As_[m][kc * 8]) =
          *(const uint4*)(attn + (size_t)(m0 + m) * D_ + k0 + kc * 8);
    }
    {
      const int g = k0 >> 7;
      const int zw = qz[g * (N2 / 8) + (gn >> 3)];
      const float zp = (float)(((zw >> ((gn & 7) * 4)) & 15) + 1);
      const float scale = sc[g * N2 + gn];
      const float szp = scale * zp;
      const int kq0 = (k0 >> 3) + brh * 4;
#pragma unroll
      for (int i = 0; i < 4; ++i) {
        const uint w = (uint)qw[(size_t)(kq0 + i) * N2 + gn];
        us8_t pk;
#pragma unroll
        for (int j = 0; j < 8; ++j)
          pk[j] = f2bf(fmaf((float)((w >> (4 * j)) & 15u), scale, -szp));
        *(us8_t*)(&Bs_[bn][(brh * 4 + i) * 8]) = pk;
      }
    }
    __syncthreads();
#pragma unroll
    for (int kk = 0; kk < 64; kk += 32) {
      bf8_t af[4], bfv[4];
#pragma unroll
      for (int i = 0; i < 4; ++i)
        af[i] = *(const bf8_t*)(&As_[wm + i * 16 + l15][kk + quad * 8]);
#pragma unroll
      for (int j = 0; j < 4; ++j)
        bfv[j] = *(const bf8_t*)(&Bs_[wn + j * 16 + l15][kk + quad * 8]);
#pragma unroll
      for (int i = 0; i < 4; ++i)
#pragma unroll
        for (int j = 0; j < 4; ++j)
          acc[i][j] = MFMA16(af[i], bfv[j], acc[i][j]);
    }
    __syncthreads();
  }
#pragma unroll
  for (int i = 0; i < 4; ++i) {
#pragma unroll
    for (int r = 0; r < 4; ++r) {
      float* prow = out + (size_t)(m0 + wm + i * 16 + quad * 4 + r) * D_ + n0 + wn + l15;
#pragma unroll
      for (int j = 0; j < 4; ++j)
        prow[j * 16] = acc[i][j][r];
    }
  }
}

// ---------------------------------------------------------------------------
extern "C" void kernel_launch(void* const* d_in, const int* in_sizes, int n_in,
                              void* d_out, int out_size, void* d_ws, size_t ws_size,
                              hipStream_t stream)
{
  const float* hid    = (const float*)d_in[0];
  const int*   qw_qkv = (const int*)d_in[1];
  const int*   qz_qkv = (const int*)d_in[2];
  const float* sc_qkv = (const float*)d_in[3];
  const int*   qw_out = (const int*)d_in[4];
  const int*   qz_out = (const int*)d_in[5];
  const float* sc_out = (const float*)d_in[6];
  float* out = (float*)d_out;

  const size_t QKV_E = (size_t)B_ * H_ * S_ * HD_;   // 16,777,216 elems

  if (ws_size >= (size_t)268435456) {
    // fast path: exactly 256 MiB layout
    ushort* hidA  = (ushort*)d_ws;          // 33.5 MB (aliased by attn later)
    ushort* wsq   = hidA + QKV_E;
    ushort* wsk   = wsq + QKV_E;
    ushort* wsv   = wsk + QKV_E;
    ushort* wsvt  = wsv + QKV_E;
    ushort* wT    = wsvt + QKV_E;           // 100.7 MB (Wqkv^T, then Wout^T)
    ushort* wsattn = hidA;                  // alias: hidA dead after gemm_fast_qkv

    cvt_bf16<<<dim3(8192), 256, 0, stream>>>(hid, hidA);
    dequant_w<<<dim3(192, 64), 256, 0, stream>>>(qw_qkv, qz_qkv, sc_qkv, wT, N1);
    gemm_fast_qkv<<<dim3(48, 16), 512, 0, stream>>>(hidA, wT, wsq, wsk, wsv);
    rope_qk<<<dim3(16384), 256, 0, stream>>>(wsq, wsk);
    transpose_v<<<dim3(32, 4, 32), 256, 0, stream>>>(wsv, wsvt);
    flash_attn2<<<dim3(32, 32), 256, 0, stream>>>(wsq, wsk, wsvt, wsattn);
    dequant_w<<<dim3(64, 64), 256, 0, stream>>>(qw_out, qz_out, sc_out, wT, N2);
    gemm_fast_out<<<dim3(16, 16), 512, 0, stream>>>(wsattn, wT, out);
  } else {
    // fallback path (168 MB)
    ushort* wsq    = (ushort*)d_ws;
    ushort* wsk    = wsq + QKV_E;
    ushort* wsv    = wsk + QKV_E;
    ushort* wsvt   = wsv + QKV_E;
    ushort* wsattn = wsvt + QKV_E;

    gemm_qkv_fb<<<dim3(96, 32), 256, 0, stream>>>(hid, qw_qkv, qz_qkv, sc_qkv, wsq, wsk, wsv);
    rope_qk<<<dim3(16384), 256, 0, stream>>>(wsq, wsk);
    transpose_v<<<dim3(32, 4, 32), 256, 0, stream>>>(wsv, wsvt);
    flash_attn2<<<dim3(32, 32), 256, 0, stream>>>(wsq, wsk, wsvt, wsattn);
    gemm_out_fb<<<dim3(32, 32), 256, 0, stream>>>(wsattn, qw_out, qz_out, sc_out, out);
  }
}

// Round 3
// 778.457 us; speedup vs baseline: 1.2312x; 1.2210x over previous
//
#include <hip/hip_runtime.h>

#define B_  2
#define S_  2048
#define D_  4096
#define H_  16
#define HD_ 256
#define N1  12288
#define N2  4096

typedef __attribute__((ext_vector_type(8))) short  bf8_t;   // 8 bf16 (4 VGPRs)
typedef __attribute__((ext_vector_type(8))) ushort us8_t;
typedef __attribute__((ext_vector_type(4))) float  f4_t;

__device__ __forceinline__ ushort f2bf(float f) {
  union { float f; uint u; } c; c.f = f;
  uint u = c.u;
  return (ushort)((u + 0x7fffu + ((u >> 16) & 1u)) >> 16);  // RNE
}
__device__ __forceinline__ float bf2f(ushort b) {
  union { uint u; float f; } c; c.u = ((uint)b) << 16;
  return c.f;
}

#define MFMA16(a, b, c) __builtin_amdgcn_mfma_f32_16x16x32_bf16((a), (b), (c), 0, 0, 0)

__device__ __forceinline__ void gload16(const void* g, void* l) {
  __builtin_amdgcn_global_load_lds(
      (const __attribute__((address_space(1))) void*)g,
      (__attribute__((address_space(3))) void*)l, 16, 0, 0);
}

// ---------------------------------------------------------------------------
// hidden f32 -> bf16
// ---------------------------------------------------------------------------
__global__ __launch_bounds__(256) void cvt_bf16(const float* __restrict__ x,
                                                ushort* __restrict__ y)
{
  const size_t i = ((size_t)blockIdx.x * 256 + threadIdx.x) * 8;
  const float4 a = *(const float4*)(x + i);
  const float4 b = *(const float4*)(x + i + 4);
  us8_t o;
  o[0] = f2bf(a.x); o[1] = f2bf(a.y); o[2] = f2bf(a.z); o[3] = f2bf(a.w);
  o[4] = f2bf(b.x); o[5] = f2bf(b.y); o[6] = f2bf(b.z); o[7] = f2bf(b.w);
  *(us8_t*)(y + i) = o;
}

// ---------------------------------------------------------------------------
// GPTQ dequant -> W^T bf16 [N][4096]  (one-shot, memory-bound)
// ---------------------------------------------------------------------------
__global__ __launch_bounds__(256) void dequant_w(
    const int* __restrict__ qw, const int* __restrict__ qz,
    const float* __restrict__ sc, ushort* __restrict__ wt, const int N)
{
  __shared__ ushort T[64][72];
  const int tid = threadIdx.x;
  const int n0 = blockIdx.x * 64, k0 = blockIdx.y * 64;
  const int g = k0 >> 7;                           // GS=128
  const int nn  = tid & 63;
  const int kw0 = tid >> 6;                        // 0..3
  const int gn = n0 + nn;
  const int zw = qz[g * (N >> 3) + (gn >> 3)];
  const float zp = (float)(((zw >> ((gn & 7) * 4)) & 15) + 1);
  const float scale = sc[g * N + gn];
  const float szp = scale * zp;
#pragma unroll
  for (int t = 0; t < 2; ++t) {
    const int kw = kw0 + t * 4;
    const uint w = (uint)qw[(size_t)((k0 >> 3) + kw) * N + gn];
    us8_t pk;
#pragma unroll
    for (int j = 0; j < 8; ++j)
      pk[j] = f2bf(fmaf((float)((w >> (4 * j)) & 15u), scale, -szp));
    *(us8_t*)(&T[nn][kw * 8]) = pk;
  }
  __syncthreads();
#pragma unroll
  for (int t = 0; t < 2; ++t) {
    const int u = tid + t * 256;
    const int r = u >> 3, c = u & 7;
    *(uint4*)(wt + (size_t)(n0 + r) * 4096 + k0 + c * 8) = *(uint4*)(&T[r][c * 8]);
  }
}

// ---------------------------------------------------------------------------
// 256x256 bf16 GEMM core: 4-deep pipeline, ONE fence per K-tile,
// compiler-scheduled ds_read<->MFMA interleave (m97-style fine lgkmcnt),
// counted vmcnt (T4) so global_load_lds stays in flight across barriers.
//
// Geometry: BM=BN=256, BK=32, 8 waves (2M x 4N), wave tile 128x64,
// 4-deep circular LDS buffer (128 KiB), stage 3 tiles ahead.
//
// Per K-tile t (unrolled x4 so buffer idx is compile-time):
//   STAGE tile t+3 into buf[(t+3)&3]   (4 x global_load_lds)
//   ds_read 12 x b128 from buf[t&3]    (NO manual lgkm drain)
//   32 MFMA                            (compiler inserts lgkmcnt(N))
//   s_waitcnt vmcnt(8)                 (retires tile t+1's 4 loads)
//   s_barrier + sched_barrier(0)       (single fence point per tile)
// Hazards: RAW on buf[t+1] covered by vmcnt(8)+barrier; WAR on buf[t&3]
// (overwritten by gloads issued in iter t+1) covered by the barrier since
// all reads are register-consumed (compiler lgkm waits) before it.
// Tail peels vmcnt 8->4->0; never drains to 0 in the main loop.
// LDS swizzle: slot s of 128B row-pair p holds global 16B chunk s^(p&7),
// applied on BOTH the pre-swizzled global source and the ds_read offsets.
// ---------------------------------------------------------------------------
#define NT_ 128   /* 4096 / 32 */

#define STAGE_AB(t_, b_) do {                                                 \
    const int kk_ = (t_) << 5;                                                \
    gload16(Arow0 + kk_,                      &As[b_][wave * 512]);           \
    gload16(Arow0 + (size_t)128 * 4096 + kk_, &As[b_][4096 + wave * 512]);    \
    gload16(Brow0 + kk_,                      &Bs[b_][wave * 512]);           \
    gload16(Brow0 + (size_t)128 * 4096 + kk_, &Bs[b_][4096 + wave * 512]);    \
  } while (0)

#define NOSTAGE do { } while (0)

#define VMW(n_) asm volatile("s_waitcnt vmcnt(" #n_ ")" ::: "memory")
#define NOVMW   do { } while (0)

#define TILE_T(b_, STAGE_, VMWAIT_) do {                                      \
    STAGE_;                                                                   \
    const char* ab_ = (const char*)(&As[b_][0]);                              \
    const char* bb_ = (const char*)(&Bs[b_][0]);                              \
    bf8_t af[8], bfv[4];                                                      \
    _Pragma("unroll") for (int i = 0; i < 8; ++i)                             \
        af[i] = *(const bf8_t*)(ab_ + aoff[i]);                               \
    _Pragma("unroll") for (int j = 0; j < 4; ++j)                             \
        bfv[j] = *(const bf8_t*)(bb_ + boff[j]);                              \
    _Pragma("unroll") for (int i = 0; i < 8; ++i)                             \
    _Pragma("unroll") for (int j = 0; j < 4; ++j)                             \
        acc[i][j] = MFMA16(af[i], bfv[j], acc[i][j]);                         \
    VMWAIT_;                                                                  \
    __builtin_amdgcn_s_barrier();                                             \
    __builtin_amdgcn_sched_barrier(0);                                        \
  } while (0)

#define GEMM256_CORE(Ag_, Bg_)                                                \
  __shared__ ushort As[4][8192];                                              \
  __shared__ ushort Bs[4][8192];                                              \
  const int tid  = threadIdx.x;                                               \
  const int lane = tid & 63, wave = tid >> 6;                                 \
  const int quad = lane >> 4, l15 = lane & 15;                                \
  const int wm = wave >> 2, wn = wave & 3;                                    \
  const int gx = gridDim.x;                                                   \
  int lin = blockIdx.y * gx + blockIdx.x;                                     \
  lin = (lin & 7) * (gx << 1) + (lin >> 3); /* bijective: nwg = gx*16, %8==0 */\
  const int n0 = (lin >> 4) << 8;                                             \
  const int m0 = (lin & 15) << 8;                                             \
  f4_t acc[8][4];                                                             \
  _Pragma("unroll") for (int i = 0; i < 8; ++i)                               \
  _Pragma("unroll") for (int j = 0; j < 4; ++j)                               \
      acc[i][j] = (f4_t){0.f, 0.f, 0.f, 0.f};                                 \
  /* staging: linear chunk q = rr*512 + tid; p=q>>3 (128B pair), s=q&7 */     \
  const int pq   = tid >> 3;                                                  \
  const int gch  = (tid & 7) ^ (pq & 7);                                      \
  const int grow = 2 * pq + (gch >> 2);                                       \
  const int gcol = (gch & 3) * 8;                                             \
  const ushort* Arow0 = Ag_ + (size_t)(m0 + grow) * 4096 + gcol;              \
  const ushort* Brow0 = Bg_ + (size_t)(n0 + grow) * 4096 + gcol;              \
  /* ds_read offsets: row R -> pair p=R>>1, slot ((R&1)*4+quad)^(p&7) */      \
  const int h_ = l15 >> 1;                                                    \
  const int sx = ((l15 & 1) * 4 + quad) ^ h_;                                 \
  int aoff[8], boff[4];                                                       \
  _Pragma("unroll") for (int i = 0; i < 8; ++i)                               \
      aoff[i] = (((wm * 64 + i * 8 + h_) * 8) + sx) * 16;                     \
  _Pragma("unroll") for (int j = 0; j < 4; ++j)                               \
      boff[j] = (((wn * 32 + j * 8 + h_) * 8) + sx) * 16;                     \
  STAGE_AB(0, 0);                                                             \
  STAGE_AB(1, 1);                                                             \
  STAGE_AB(2, 2);                                                             \
  VMW(8);                                                                     \
  __builtin_amdgcn_s_barrier();                                               \
  __builtin_amdgcn_sched_barrier(0);                                          \
  for (int t = 0; t + 7 < NT_; t += 4) {                                      \
    TILE_T(0, STAGE_AB(t + 3, 3), VMW(8));                                    \
    TILE_T(1, STAGE_AB(t + 4, 0), VMW(8));                                    \
    TILE_T(2, STAGE_AB(t + 5, 1), VMW(8));                                    \
    TILE_T(3, STAGE_AB(t + 6, 2), VMW(8));                                    \
  }                                                                           \
  /* tiles 124..127 */                                                        \
  TILE_T(0, STAGE_AB(NT_ - 1, 3), VMW(8));                                    \
  TILE_T(1, NOSTAGE, VMW(4));                                                 \
  TILE_T(2, NOSTAGE, VMW(0));                                                 \
  TILE_T(3, NOSTAGE, NOVMW);

__global__ __launch_bounds__(512, 2) void gemm_fast_qkv(
    const ushort* __restrict__ A, const ushort* __restrict__ BT,
    ushort* __restrict__ wq, ushort* __restrict__ wk, ushort* __restrict__ wv)
{
  GEMM256_CORE(A, BT)
  // epilogue: scatter to (which, B, H, S, hd) bf16; q prescaled by 1/sqrt(hd)
  // n0 is a multiple of 256 -> tile covers exactly one head's 256 dims.
  const int which = n0 >> 12;
  const int nh = (n0 & 4095) >> 8;
  const int bb = m0 >> 11;
  const int s_base = m0 & 2047;
  ushort* dst = (which == 0) ? wq : (which == 1) ? wk : wv;
  const float osc = (which == 0) ? 0.0625f : 1.0f;
  const size_t rowbase = ((size_t)bb * H_ + nh) * S_;
#pragma unroll
  for (int i = 0; i < 8; ++i) {
#pragma unroll
    for (int r = 0; r < 4; ++r) {
      const int s = s_base + wm * 128 + i * 16 + quad * 4 + r;
      ushort* prow = dst + (rowbase + s) * HD_ + wn * 64 + l15;
#pragma unroll
      for (int j = 0; j < 4; ++j)
        prow[j * 16] = f2bf(acc[i][j][r] * osc);
    }
  }
}

__global__ __launch_bounds__(512, 2) void gemm_fast_out(
    const ushort* __restrict__ A, const ushort* __restrict__ BT,
    float* __restrict__ out)
{
  GEMM256_CORE(A, BT)
#pragma unroll
  for (int i = 0; i < 8; ++i) {
#pragma unroll
    for (int r = 0; r < 4; ++r) {
      float* prow = out + (size_t)(m0 + wm * 128 + i * 16 + quad * 4 + r) * D_
                        + n0 + wn * 64 + l15;
#pragma unroll
      for (int j = 0; j < 4; ++j)
        prow[j * 16] = acc[i][j][r];
    }
  }
}

// ---------------------------------------------------------------------------
// RoPE in-place on q and k (q is prescaled; rotation commutes with scalar)
// ---------------------------------------------------------------------------
__global__ __launch_bounds__(256) void rope_qk(ushort* __restrict__ q, ushort* __restrict__ k)
{
  const int idx = blockIdx.x * 256 + threadIdx.x;
  const int i   = idx & 31;
  const int row = (idx >> 5) & 0xFFFF;
  const int buf = idx >> 21;
  const int s   = row & 2047;
  ushort* p = (buf ? k : q) + (size_t)row * HD_ + 2 * i;
  const float inv_freq = expf((float)(2 * i) * -0.14391157f);
  const float ang = (float)s * inv_freq;
  float sn, cs;
  sincosf(ang, &sn, &cs);
  uint pr = *(uint*)p;
  const float x1 = bf2f((ushort)(pr & 0xFFFF));
  const float x2 = bf2f((ushort)(pr >> 16));
  const uint lo = f2bf(x1 * cs - x2 * sn);
  const uint hi = f2bf(x2 * cs + x1 * sn);
  *(uint*)p = lo | (hi << 16);
}

// ---------------------------------------------------------------------------
// V (B,H,S,hd) -> VT (B,H,hd,S)
// ---------------------------------------------------------------------------
__global__ __launch_bounds__(256) void transpose_v(const ushort* __restrict__ v,
                                                   ushort* __restrict__ vt)
{
  __shared__ uint t32[64][65];
  const int tid = threadIdx.x;
  const int s0 = blockIdx.x * 64, d0 = blockIdx.y * 64, bh = blockIdx.z;
  const ushort* src = v + ((size_t)bh * S_ + s0) * HD_ + d0;
#pragma unroll
  for (int i = 0; i < 2; ++i) {
    const int u = tid + 256 * i;
    const int r = u >> 3, cu = u & 7;
    const uint4 val = *(const uint4*)(src + (size_t)r * HD_ + cu * 8);
    const ushort* pv = (const ushort*)&val;
#pragma unroll
    for (int j = 0; j < 8; ++j) t32[r][cu * 8 + j] = pv[j];
  }
  __syncthreads();
  ushort* dstb = vt + ((size_t)bh * HD_ + d0) * S_ + s0;
#pragma unroll
  for (int i = 0; i < 2; ++i) {
    const int u = tid + 256 * i;
    const int dr = u >> 3, cu = u & 7;
    union { ushort u16[8]; uint4 v4; } tmp;
#pragma unroll
    for (int j = 0; j < 8; ++j) tmp.u16[j] = (ushort)t32[cu * 8 + j][dr];
    *(uint4*)(dstb + (size_t)dr * S_ + cu * 8) = tmp.v4;
  }
}

// ---------------------------------------------------------------------------
// Flash attention v2: ones-column l, rescale-skip, swizzled global_load_lds K
// Q is prescaled by 1/sqrt(hd). Grid: (bh, qtile) with qtile heavy-first.
// ---------------------------------------------------------------------------
__global__ __launch_bounds__(256) void flash_attn2(
    const ushort* __restrict__ Q, const ushort* __restrict__ K,
    const ushort* __restrict__ VT, ushort* __restrict__ attn)
{
  __shared__ ushort Kls[8192];         // 32 keys x 256 c, 16B-chunk swizzled
  __shared__ ushort Vls[256][40];      // [d][key] +8 pad
  __shared__ ushort Pls[4][16][40];    // per-wave P roundtrip
  const int tid  = threadIdx.x;
  const int lane = tid & 63, wave = tid >> 6;
  const int quad = lane >> 4, l15 = lane & 15;
  const int bh = blockIdx.x;
  const int qt = 31 - blockIdx.y;      // heavy blocks dispatched first

  const ushort* qb = Q + ((size_t)bh * S_ + qt * 64 + wave * 16 + l15) * HD_;
  bf8_t qf[8];
#pragma unroll
  for (int c = 0; c < 8; ++c)
    qf[c] = *(const bf8_t*)(qb + c * 32 + quad * 8);

  bf8_t onef;
#pragma unroll
  for (int j = 0; j < 8; ++j) onef[j] = (short)0x3f80;   // 1.0 bf16

  f4_t o[16];
#pragma unroll
  for (int i = 0; i < 16; ++i) o[i] = (f4_t){0.f, 0.f, 0.f, 0.f};
  f4_t ol = (f4_t){0.f, 0.f, 0.f, 0.f};                 // l accumulator
  float m_r[4] = {-1e30f, -1e30f, -1e30f, -1e30f};

  const int qrow0 = qt * 64 + wave * 16 + quad * 4;
  const int wave_min_row = qt * 64 + wave * 16;
  const int nkt = 2 * (qt + 1);
  const ushort* kb0 = K + (size_t)bh * S_ * HD_;
  const ushort* vb0 = VT + (size_t)bh * HD_ * S_;

  // staging indices (K): chunk c covers rows c*2..c*2+1 (512B each)
  const int st_row_off = lane >> 5;    // 0/1
  const int st_u = lane & 31;

  for (int kt = 0; kt < nkt; ++kt) {
    const int key0 = kt * 32;
    __syncthreads();
    // K: global_load_lds, 16B-chunk XOR swizzle in the GLOBAL address
#pragma unroll
    for (int i = 0; i < 4; ++i) {
      const int c = wave * 4 + i;
      const int row = c * 2 + st_row_off;
      const int g = st_u ^ (row & 7);
      gload16(kb0 + (size_t)(key0 + row) * HD_ + g * 8, &Kls[c * 512]);
    }
    // V: VGPR roundtrip staging
#pragma unroll
    for (int i = 0; i < 4; ++i) {
      const int u = tid + 256 * i;
      const int d = u >> 2, cu = u & 3;
      *(uint4*)(&Vls[d][cu * 8]) =
          *(const uint4*)(vb0 + (size_t)d * S_ + key0 + cu * 8);
    }
    __syncthreads();

    // S = Q K^T : 16 x 32 (swizzled Kls reads)
    f4_t sf0 = (f4_t){0.f, 0.f, 0.f, 0.f};
    f4_t sf1 = (f4_t){0.f, 0.f, 0.f, 0.f};
    const int sx = l15 & 7;
#pragma unroll
    for (int cc = 0; cc < 8; ++cc) {
      const int w = cc * 4 + quad;
      const bf8_t b0 = *(const bf8_t*)(&Kls[l15 * 256 + (w ^ sx) * 8]);
      const bf8_t b1 = *(const bf8_t*)(&Kls[(16 + l15) * 256 + (w ^ sx) * 8]);
      sf0 = MFMA16(qf[cc], b0, sf0);
      sf1 = MFMA16(qf[cc], b1, sf1);
    }

    // mask (only when tile crosses the diagonal for this wave)
    float mt[4];
    if (key0 + 31 <= wave_min_row) {
#pragma unroll
      for (int r = 0; r < 4; ++r) mt[r] = fmaxf(sf0[r], sf1[r]);
    } else {
#pragma unroll
      for (int r = 0; r < 4; ++r) {
        const int qr = qrow0 + r;
        sf0[r] = (key0 + l15 <= qr)      ? sf0[r] : -1e30f;
        sf1[r] = (key0 + 16 + l15 <= qr) ? sf1[r] : -1e30f;
        mt[r] = fmaxf(sf0[r], sf1[r]);
      }
    }
#pragma unroll
    for (int off = 1; off < 16; off <<= 1)
#pragma unroll
      for (int r = 0; r < 4; ++r)
        mt[r] = fmaxf(mt[r], __shfl_xor(mt[r], off));

    // rescale only when the running max grew (rare)
    const bool chg = (mt[0] > m_r[0]) | (mt[1] > m_r[1]) |
                     (mt[2] > m_r[2]) | (mt[3] > m_r[3]);
    if (__any(chg)) {
      float alpha[4];
#pragma unroll
      for (int r = 0; r < 4; ++r) {
        const float mn = fmaxf(m_r[r], mt[r]);
        alpha[r] = __expf(m_r[r] - mn);
        m_r[r] = mn;
      }
#pragma unroll
      for (int i = 0; i < 16; ++i)
#pragma unroll
        for (int r = 0; r < 4; ++r)
          o[i][r] *= alpha[r];
#pragma unroll
      for (int r = 0; r < 4; ++r) ol[r] *= alpha[r];
    }
#pragma unroll
    for (int r = 0; r < 4; ++r) {
      sf0[r] = __expf(sf0[r] - m_r[r]);
      sf1[r] = __expf(sf1[r] - m_r[r]);
    }

    // P (C-layout) -> LDS -> A-layout; wave-private
#pragma unroll
    for (int r = 0; r < 4; ++r) {
      Pls[wave][quad * 4 + r][l15]      = f2bf(sf0[r]);
      Pls[wave][quad * 4 + r][16 + l15] = f2bf(sf1[r]);
    }
    const bf8_t ap = *(const bf8_t*)(&Pls[wave][l15][quad * 8]);

    // O += P V ; l += P 1
    ol = MFMA16(ap, onef, ol);
#pragma unroll
    for (int df = 0; df < 16; ++df) {
      const bf8_t bv = *(const bf8_t*)(&Vls[df * 16 + l15][quad * 8]);
      o[df] = MFMA16(ap, bv, o[df]);
    }
  }

  // epilogue: attn (B,S,D) bf16
  const int b = bh >> 4, h = bh & 15;
  float inv[4];
#pragma unroll
  for (int r = 0; r < 4; ++r) inv[r] = 1.0f / ol[r];
#pragma unroll
  for (int r = 0; r < 4; ++r) {
    const int s = qt * 64 + wave * 16 + quad * 4 + r;
    ushort* prow = attn + ((size_t)b * S_ + s) * D_ + h * HD_ + l15;
#pragma unroll
    for (int df = 0; df < 16; ++df)
      prow[df * 16] = f2bf(o[df][r] * inv[r]);
  }
}

// ---------------------------------------------------------------------------
// FALLBACK (dequant-in-GEMM), used only if ws < 256 MiB
// ---------------------------------------------------------------------------
__global__ __launch_bounds__(256) void gemm_qkv_fb(
    const float* __restrict__ hid, const int* __restrict__ qw,
    const int* __restrict__ qz, const float* __restrict__ sc,
    ushort* __restrict__ wq, ushort* __restrict__ wk, ushort* __restrict__ wv)
{
  __shared__ ushort As_[128][72];
  __shared__ ushort Bs_[128][72];
  const int tid  = threadIdx.x;
  const int lane = tid & 63, wave = tid >> 6;
  const int quad = lane >> 4, l15 = lane & 15;
  const int n0 = blockIdx.x * 128, m0 = blockIdx.y * 128;
  f4_t acc[4][4];
#pragma unroll
  for (int i = 0; i < 4; ++i)
#pragma unroll
    for (int j = 0; j < 4; ++j) acc[i][j] = (f4_t){0.f, 0.f, 0.f, 0.f};
  const int bn  = tid & 127;
  const int brh = tid >> 7;
  const int gn  = n0 + bn;
  const int wm = (wave >> 1) * 64, wn = (wave & 1) * 64;
  for (int k0 = 0; k0 < D_; k0 += 64) {
#pragma unroll
    for (int i = 0; i < 8; ++i) {
      const int u = tid + 256 * i;
      const int m = u >> 4, kc = u & 15;
      const float4 v = *(const float4*)(hid + (size_t)(m0 + m) * D_ + k0 + kc * 4);
      ushort4 b;
      b.x = f2bf(v.x); b.y = f2bf(v.y); b.z = f2bf(v.z); b.w = f2bf(v.w);
      *(ushort4*)(&As_[m][kc * 4]) = b;
    }
    {
      const int g = k0 >> 7;
      const int zw = qz[g * (N1 / 8) + (gn >> 3)];
      const float zp = (float)(((zw >> ((gn & 7) * 4)) & 15) + 1);
      const float scale = sc[g * N1 + gn];
      const float szp = scale * zp;
      const int kq0 = (k0 >> 3) + brh * 4;
#pragma unroll
      for (int i = 0; i < 4; ++i) {
        const uint w = (uint)qw[(size_t)(kq0 + i) * N1 + gn];
        us8_t pk;
#pragma unroll
        for (int j = 0; j < 8; ++j)
          pk[j] = f2bf(fmaf((float)((w >> (4 * j)) & 15u), scale, -szp));
        *(us8_t*)(&Bs_[bn][(brh * 4 + i) * 8]) = pk;
      }
    }
    __syncthreads();
#pragma unroll
    for (int kk = 0; kk < 64; kk += 32) {
      bf8_t af[4], bfv[4];
#pragma unroll
      for (int i = 0; i < 4; ++i)
        af[i] = *(const bf8_t*)(&As_[wm + i * 16 + l15][kk + quad * 8]);
#pragma unroll
      for (int j = 0; j < 4; ++j)
        bfv[j] = *(const bf8_t*)(&Bs_[wn + j * 16 + l15][kk + quad * 8]);
#pragma unroll
      for (int i = 0; i < 4; ++i)
#pragma unroll
        for (int j = 0; j < 4; ++j)
          acc[i][j] = MFMA16(af[i], bfv[j], acc[i][j]);
    }
    __syncthreads();
  }
  const int which = n0 >> 12;
  const int nh = (n0 & 4095) >> 8;
  const int d0 = n0 & 255;
  const int bb = m0 >> 11;
  const int s_base = m0 & 2047;
  ushort* dst = (which == 0) ? wq : (which == 1) ? wk : wv;
  const float osc = (which == 0) ? 0.0625f : 1.0f;
  const size_t rowbase = ((size_t)bb * H_ + nh) * S_;
#pragma unroll
  for (int i = 0; i < 4; ++i) {
#pragma unroll
    for (int r = 0; r < 4; ++r) {
      const int s = s_base + wm + i * 16 + quad * 4 + r;
      ushort* prow = dst + (rowbase + s) * HD_ + d0 + wn + l15;
#pragma unroll
      for (int j = 0; j < 4; ++j)
        prow[j * 16] = f2bf(acc[i][j][r] * osc);
    }
  }
}

__global__ __launch_bounds__(256) void gemm_out_fb(
    const ushort* __restrict__ attn, const int* __restrict__ qw,
    const int* __restrict__ qz, const float* __restrict__ sc,
    float* __restrict__ out)
{
  __shared__ ushort As_[128][72];
  __shared__ ushort Bs_[128][72];
  const int tid  = threadIdx.x;
  const int lane = tid & 63, wave = tid >> 6;
  const int quad = lane >> 4, l15 = lane & 15;
  const int n0 = blockIdx.x * 128, m0 = blockIdx.y * 128;
  f4_t acc[4][4];
#pragma unroll
  for (int i = 0; i < 4; ++i)
#pragma unroll
    for (int j = 0; j < 4; ++j) acc[i][j] = (f4_t){0.f, 0.f, 0.f, 0.f};
  const int bn  = tid & 127;
  const int brh = tid >> 7;
  const int gn  = n0 + bn;
  const int wm = (wave >> 1) * 64, wn = (wave & 1) * 64;
  for (int k0 = 0; k0 < D_; k0 += 64) {
#pragma unroll
    for (int i = 0; i < 4; ++i) {
      const int u = tid + 256 * i;
      const int m = u >> 3, kc = u & 7;
      *(uint4*)(&As_[m][kc * 8]) =
          *(const uint4*)(attn + (size_t)(m0 + m) * D_ + k0 + kc * 8);
    }
    {
      const int g = k0 >> 7;
      const int zw = qz[g * (N2 / 8) + (gn >> 3)];
      const float zp = (float)(((zw >> ((gn & 7) * 4)) & 15) + 1);
      const float scale = sc[g * N2 + gn];
      const float szp = scale * zp;
      const int kq0 = (k0 >> 3) + brh * 4;
#pragma unroll
      for (int i = 0; i < 4; ++i) {
        const uint w = (uint)qw[(size_t)(kq0 + i) * N2 + gn];
        us8_t pk;
#pragma unroll
        for (int j = 0; j < 8; ++j)
          pk[j] = f2bf(fmaf((float)((w >> (4 * j)) & 15u), scale, -szp));
        *(us8_t*)(&Bs_[bn][(brh * 4 + i) * 8]) = pk;
      }
    }
    __syncthreads();
#pragma unroll
    for (int kk = 0; kk < 64; kk += 32) {
      bf8_t af[4], bfv[4];
#pragma unroll
      for (int i = 0; i < 4; ++i)
        af[i] = *(const bf8_t*)(&As_[wm + i * 16 + l15][kk + quad * 8]);
#pragma unroll
      for (int j = 0; j < 4; ++j)
        bfv[j] = *(const bf8_t*)(&Bs_[wn + j * 16 + l15][kk + quad * 8]);
#pragma unroll
      for (int i = 0; i < 4; ++i)
#pragma unroll
        for (int j = 0; j < 4; ++j)
          acc[i][j] = MFMA16(af[i], bfv[j], acc[i][j]);
    }
    __syncthreads();
  }
#pragma unroll
  for (int i = 0; i < 4; ++i) {
#pragma unroll
    for (int r = 0; r < 4; ++r) {
      float* prow = out + (size_t)(m0 + wm + i * 16 + quad * 4 + r) * D_ + n0 + wn + l15;
#pragma unroll
      for (int j = 0; j < 4; ++j)
        prow[j * 16] = acc[i][j][r];
    }
  }
}

// ---------------------------------------------------------------------------
extern "C" void kernel_launch(void* const* d_in, const int* in_sizes, int n_in,
                              void* d_out, int out_size, void* d_ws, size_t ws_size,
                              hipStream_t stream)
{
  const float* hid    = (const float*)d_in[0];
  const int*   qw_qkv = (const int*)d_in[1];
  const int*   qz_qkv = (const int*)d_in[2];
  const float* sc_qkv = (const float*)d_in[3];
  const int*   qw_out = (const int*)d_in[4];
  const int*   qz_out = (const int*)d_in[5];
  const float* sc_out = (const float*)d_in[6];
  float* out = (float*)d_out;

  const size_t QKV_E = (size_t)B_ * H_ * S_ * HD_;   // 16,777,216 elems

  if (ws_size >= (size_t)268435456) {
    // fast path: exactly 256 MiB layout
    ushort* hidA  = (ushort*)d_ws;          // 33.5 MB (aliased by attn later)
    ushort* wsq   = hidA + QKV_E;
    ushort* wsk   = wsq + QKV_E;
    ushort* wsv   = wsk + QKV_E;
    ushort* wsvt  = wsv + QKV_E;
    ushort* wT    = wsvt + QKV_E;           // 100.7 MB (Wqkv^T, then Wout^T)
    ushort* wsattn = hidA;                  // alias: hidA dead after gemm_fast_qkv

    cvt_bf16<<<dim3(8192), 256, 0, stream>>>(hid, hidA);
    dequant_w<<<dim3(192, 64), 256, 0, stream>>>(qw_qkv, qz_qkv, sc_qkv, wT, N1);
    gemm_fast_qkv<<<dim3(48, 16), 512, 0, stream>>>(hidA, wT, wsq, wsk, wsv);
    rope_qk<<<dim3(16384), 256, 0, stream>>>(wsq, wsk);
    transpose_v<<<dim3(32, 4, 32), 256, 0, stream>>>(wsv, wsvt);
    flash_attn2<<<dim3(32, 32), 256, 0, stream>>>(wsq, wsk, wsvt, wsattn);
    dequant_w<<<dim3(64, 64), 256, 0, stream>>>(qw_out, qz_out, sc_out, wT, N2);
    gemm_fast_out<<<dim3(16, 16), 512, 0, stream>>>(wsattn, wT, out);
  } else {
    // fallback path (168 MB)
    ushort* wsq    = (ushort*)d_ws;
    ushort* wsk    = wsq + QKV_E;
    ushort* wsv    = wsk + QKV_E;
    ushort* wsvt   = wsv + QKV_E;
    ushort* wsattn = wsvt + QKV_E;

    gemm_qkv_fb<<<dim3(96, 32), 256, 0, stream>>>(hid, qw_qkv, qz_qkv, sc_qkv, wsq, wsk, wsv);
    rope_qk<<<dim3(16384), 256, 0, stream>>>(wsq, wsk);
    transpose_v<<<dim3(32, 4, 32), 256, 0, stream>>>(wsv, wsvt);
    flash_attn2<<<dim3(32, 32), 256, 0, stream>>>(wsq, wsk, wsvt, wsattn);
    gemm_out_fb<<<dim3(32, 32), 256, 0, stream>>>(wsattn, qw_out, qz_out, sc_out, out);
  }
}